// Round 4
// baseline (445.176 us; speedup 1.0000x reference)
//
#include <hip/hip_runtime.h>
#include <hip/hip_bf16.h>
#include <stdint.h>

#define IN_F  4096
#define OUT_F 4096
#define BSZ   4
#define SEQ   2048
#define MDIM  (BSZ * SEQ)   // 8192

// ---------------- address-space helpers for global_load_lds ----------------
typedef __attribute__((address_space(1))) uint8_t ga_u8_t;
typedef __attribute__((address_space(3))) uint8_t ls_u8_t;

__device__ __forceinline__ void gload16_lds(const void* g, void* l) {
    // 16B-wide direct global->LDS DMA (global_load_lds_dwordx4)
    __builtin_amdgcn_global_load_lds((ga_u8_t*)g, (ls_u8_t*)l, 16, 0, 0);
}

// round-to-nearest-even fp32 -> bf16, returned as fp32 value
__device__ __forceinline__ float bf16_rne(float f) {
    unsigned u = __float_as_uint(f);
    u = (u + 0x7fffu + ((u >> 16) & 1u)) & 0xffff0000u;
    return __uint_as_float(u);
}

// ---------------- pass 1: global amax of |x| ----------------
__global__ void amax_kernel(const float* __restrict__ x, int n4,
                            unsigned int* __restrict__ amax_u) {
    const float4* x4 = (const float4*)x;
    int idx = blockIdx.x * blockDim.x + threadIdx.x;
    int stride = gridDim.x * blockDim.x;
    float m = 0.0f;
    for (int i = idx; i < n4; i += stride) {
        float4 v = x4[i];
        m = fmaxf(m, fmaxf(fmaxf(fabsf(v.x), fabsf(v.y)),
                           fmaxf(fabsf(v.z), fabsf(v.w))));
    }
    for (int off = 32; off > 0; off >>= 1)
        m = fmaxf(m, __shfl_down(m, off, 64));
    __shared__ float sm[4];
    int lane = threadIdx.x & 63, wave = threadIdx.x >> 6;
    if (lane == 0) sm[wave] = m;
    __syncthreads();
    if (threadIdx.x == 0) {
        m = fmaxf(fmaxf(sm[0], sm[1]), fmaxf(sm[2], sm[3]));
        atomicMax(amax_u, __float_as_uint(m));  // valid: all values >= 0
    }
}

// ---------------- pass 2: quantize x -> int8; repack w -> packed frags ----
// W packed layout (R4): w8p[n16][kt][lane][16B], offset =
// ((n16*64 + kt)*64 + lane)*16 + b, holding W[n16*16 + (lane&15)]
// [kt*64 + (lane>>4)*16 + b]. One MFMA B-fragment == one contiguous 1KB
// block -> a wave loads it with a single coalesced global_load_dwordx4.
__global__ void prep_kernel(const float* __restrict__ x,
                            const int* __restrict__ w,
                            signed char* __restrict__ x8,
                            signed char* __restrict__ w8p,
                            const unsigned int* __restrict__ amax_u,
                            int nx4, int nwt) {
    int idx = blockIdx.x * blockDim.x + threadIdx.x;
    if (idx < nx4) {
        float amax = __uint_as_float(*amax_u);
        float xs = (amax == 0.0f) ? 1.0f : (amax / 127.0f);  // ref: amax/127
        float4 v = ((const float4*)x)[idx];
        char4 q;
        q.x = (signed char)fminf(fmaxf(rintf(v.x / xs), -127.0f), 127.0f);
        q.y = (signed char)fminf(fmaxf(rintf(v.y / xs), -127.0f), 127.0f);
        q.z = (signed char)fminf(fmaxf(rintf(v.z / xs), -127.0f), 127.0f);
        q.w = (signed char)fminf(fmaxf(rintf(v.w / xs), -127.0f), 127.0f);
        ((char4*)x8)[idx] = q;
    } else {
        int widx = idx - nx4;
        if (widx < nwt) {   // nwt = 256*64*64 threads, 16B each
            int lane = widx & 63;
            int kt   = (widx >> 6) & 63;
            int n16  = widx >> 12;
            int r  = n16 * 16 + (lane & 15);
            int kb = kt * 64 + (lane >> 4) * 16;
            const int4* src = (const int4*)(w + (size_t)r * IN_F + kb);
            int4 v0 = src[0], v1 = src[1], v2 = src[2], v3 = src[3];
            int p0 = (v0.x & 255) | ((v0.y & 255) << 8) |
                     ((v0.z & 255) << 16) | ((int)((unsigned)(v0.w & 255) << 24));
            int p1 = (v1.x & 255) | ((v1.y & 255) << 8) |
                     ((v1.z & 255) << 16) | ((int)((unsigned)(v1.w & 255) << 24));
            int p2 = (v2.x & 255) | ((v2.y & 255) << 8) |
                     ((v2.z & 255) << 16) | ((int)((unsigned)(v2.w & 255) << 24));
            int p3 = (v3.x & 255) | ((v3.y & 255) << 8) |
                     ((v3.z & 255) << 16) | ((int)((unsigned)(v3.w & 255) << 24));
            int4 out; out.x = p0; out.y = p1; out.z = p2; out.w = p3;
            ((int4*)w8p)[widx] = out;
        }
    }
}

// ---------------- pass 3: int8 GEMM, A via LDS, B direct-from-global ------
// R4: R1/R3 both landed at the same serial floor: per tile per CU, matrix
// = 1305 cy but LDS (one pipe/CU) = 96KB frag reads + 32KB staging ~ 1450
// cy, executed serially with MFMA because all 8 waves are tile-synced and
// only 1 block/CU is resident. Barrier placement (R1 8/tile vs R3 1/tile)
// didn't change it. Fix the DATA PATH instead: B operands come straight
// from global memory in fragment-packed layout (1KB coalesced dwordx4 per
// frag, prefetched one full tile ahead into a second register bank; L2-
// resident). LDS holds A only (3 x 16KB buffers): per-tile LDS = 64KB reads
// + 16KB writes ~ 940 cy < 1305 matrix -> LDS off the critical path.
// All waits are compiler-managed register deps (B loads feed MFMAs ->
// counted vmcnt for free). A-staging visibility: each wave's consumption of
// B(T-1) (vmem FIFO) drains its older A(T) gload_lds before it reaches
// tile T's barrier -> barrier then publishes all waves' A(T). The empty
// asm FENCE preserves the gload_lds < B-load issue order this relies on.
// One s_barrier per tile, zero manual waitcnt in the main loop.
using i32x4 = __attribute__((ext_vector_type(4))) int;

#define FENCE() asm volatile("" ::: "memory")
#define BAR()   do { FENCE(); __builtin_amdgcn_s_barrier(); FENCE(); } while (0)
#define WAITV(N) asm volatile("s_waitcnt vmcnt(" #N ")" ::: "memory")

// One K-tile. BUF/SBUF: LDS buffer indices (0/1/2). KST: byte k-offset of
// the A tile staged (T+2). KTN: k-tile index of the B bank prefetched (T+1).
// BC: B bank consumed this tile; BN: bank filled for next tile.
#define TILEX(BUF, SBUF, KST, KTN, BC, BN, DOSTAGE, DOPREF)                  \
  {                                                                          \
    BAR();                                                                   \
    if (DOSTAGE) {                                                           \
        signed char* sb = smem + (SBUF) * 16384;                             \
        gload16_lds(gA0 + (KST), sb + dA0);                                  \
        gload16_lds(gA1 + (KST), sb + dA1);                                  \
    }                                                                        \
    FENCE(); /* keep gload_lds issued before B loads (FIFO drain arg) */     \
    if (DOPREF) {                                                            \
        _Pragma("unroll")                                                    \
        for (int j = 0; j < 4; ++j)                                          \
            BN[j] = *(const i32x4*)(wbase + j * 65536 + (KTN) * 1024);       \
    }                                                                        \
    const signed char* base = smem + (BUF) * 16384;                          \
    i32x4 aF[8];                                                             \
    _Pragma("unroll")                                                        \
    for (int i = 0; i < 8; ++i) aF[i] = *(const i32x4*)(base + aoff[i]);     \
    _Pragma("unroll")                                                        \
    for (int i = 0; i < 8; ++i)                                              \
      _Pragma("unroll")                                                      \
      for (int j = 0; j < 4; ++j)                                            \
        acc[i][j] = __builtin_amdgcn_mfma_i32_16x16x64_i8(                   \
            aF[i], BC[j], acc[i][j], 0, 0, 0);                               \
  }

__global__ __launch_bounds__(512, 2) void gemm_i8_kernel(
    const signed char* __restrict__ A,
    const signed char* __restrict__ B,       // packed w8p
    const unsigned int* __restrict__ amax_u,
    const float* __restrict__ wscale_p,
    const float* __restrict__ bias,
    float* __restrict__ out) {
    __shared__ signed char smem[3 * 16384];  // 48 KB: 3 A-tile buffers

    const int tid = threadIdx.x;      // 0..511
    const int lane = tid & 63;
    const int wave = tid >> 6;        // 0..7
    const int wm = wave >> 2;         // 0..1
    const int wn = wave & 3;          // 0..3

    // Bijective XCD swizzle: 512 blocks, 8 XCDs, chunk = 64 = 4 mt x 16 nt.
    const int bid = blockIdx.x;
    const int wg = (bid & 7) * 64 + (bid >> 3);
    const int mt = wg >> 4;           // 0..31
    const int nt = wg & 15;           // 0..15
    const int tileM = mt * 256;
    const int tileN = nt * 256;

    // A staging: 2 units per K-tile, each 8KB = 512 threads x 16B.
    // LDS dst linear (g*16); XOR swizzle applied on the GLOBAL source
    // column: LDS(row, cg) holds G(row, cg ^ ((row>>1)&3)).
    const int g = tid;
    const int srow = g >> 2;                              // 0..127
    const int scol = ((g & 3) ^ ((srow >> 1) & 3)) * 16;  // pre-swizzled
    const signed char* gA0 = A + (size_t)(tileM +       srow) * IN_F + scol;
    const signed char* gA1 = A + (size_t)(tileM + 128 + srow) * IN_F + scol;
    const int dA0 = g * 16;
    const int dA1 = 8192 + g * 16;

    // A fragment LDS offsets (within one 16KB buffer). m = lane&15,
    // k-chunk = lane>>4; read col = kc ^ ((row>>1)&3) undoes the swizzle.
    // Conflict-free (SQ_LDS_BANK_CONFLICT == 0 measured R0-R3).
    int aoff[8];
    const int kc = lane >> 4;
#pragma unroll
    for (int i = 0; i < 8; ++i) {
        int r = wm * 128 + i * 16 + (lane & 15);
        aoff[i] = r * 64 + ((kc ^ ((r >> 1) & 3)) * 16);
    }

    // B fragment base: wave wn covers n16 = nt*16 + wn*4 + j, j in [0,4).
    // frag(j, kt) = wbase + j*65536 + kt*1024 (+ lane*16), one dwordx4 each.
    const signed char* wbase =
        B + (size_t)(nt * 16 + wn * 4) * 65536 + lane * 16;

    i32x4 acc[8][4] = {};
    i32x4 b0[4], b1[4];   // B register banks (alternate per tile, static)

    // Prologue: stage A(0)->buf0, A(1)->buf1; load B(0)->b0.
    // vmcnt(6) drains the 2 oldest (A(0) units); A(1)+B(0) stay in flight.
    gload16_lds(gA0,      smem + dA0);
    gload16_lds(gA1,      smem + dA1);
    gload16_lds(gA0 + 64, smem + 16384 + dA0);
    gload16_lds(gA1 + 64, smem + 16384 + dA1);
    FENCE();
#pragma unroll
    for (int j = 0; j < 4; ++j)
        b0[j] = *(const i32x4*)(wbase + j * 65536);
    WAITV(6);

    // Main loop: 64 tiles; buffers cycle %3, banks alternate %2 -> unroll 6.
    // Tiles 0..61 stage A(T+2); tiles 0..62 prefetch B(T+1); 63 is bare.
    for (int kt = 0; kt < 60; kt += 6) {
        TILEX(0, 2, (kt + 2) * 64, kt + 1, b0, b1, 1, 1);
        TILEX(1, 0, (kt + 3) * 64, kt + 2, b1, b0, 1, 1);
        TILEX(2, 1, (kt + 4) * 64, kt + 3, b0, b1, 1, 1);
        TILEX(0, 2, (kt + 5) * 64, kt + 4, b1, b0, 1, 1);
        TILEX(1, 0, (kt + 6) * 64, kt + 5, b0, b1, 1, 1);
        TILEX(2, 1, (kt + 7) * 64, kt + 6, b1, b0, 1, 1);
    }
    TILEX(0, 2, 62 * 64, 61, b0, b1, 1, 1);   // tile 60
    TILEX(1, 0, 63 * 64, 62, b1, b0, 1, 1);   // tile 61
    TILEX(2, 0, 0,       63, b0, b1, 0, 1);   // tile 62 (prefetch B(63))
    TILEX(0, 0, 0,       0,  b1, b0, 0, 0);   // tile 63

    // Epilogue: out = fp32( bf16(acc) * bf16(xs*ws) ) + bias
    float amax = __uint_as_float(*amax_u);
    float xs = (amax == 0.0f) ? 1.0f : (amax / 127.0f);
    float cs = bf16_rne(xs * wscale_p[0]);

    // C/D layout (16x16): col = lane&15, row = (lane>>4)*4 + reg
#pragma unroll
    for (int j = 0; j < 4; ++j) {
        int n = tileN + wn * 64 + j * 16 + (lane & 15);
        float bz = bias[n];
#pragma unroll
        for (int i = 0; i < 8; ++i) {
            int row0 = tileM + wm * 128 + i * 16 + (lane >> 4) * 4;
#pragma unroll
            for (int r = 0; r < 4; ++r) {
                float v = bf16_rne((float)acc[i][j][r]);
                float p = bf16_rne(v * cs);
                // nontemporal: don't let the 128MB output evict A/B in L2/LLC
                __builtin_nontemporal_store(
                    p + bz, &out[(size_t)(row0 + r) * OUT_F + n]);
            }
        }
    }
}

// ---------------- launch ----------------
extern "C" void kernel_launch(void* const* d_in, const int* in_sizes, int n_in,
                              void* d_out, int out_size, void* d_ws,
                              size_t ws_size, hipStream_t stream) {
    const float* x = (const float*)d_in[0];
    const int* w_int = (const int*)d_in[1];
    const float* w_scale = (const float*)d_in[2];
    const float* bias = (const float*)d_in[3];
    float* out = (float*)d_out;

    unsigned char* ws = (unsigned char*)d_ws;
    unsigned int* amax_u = (unsigned int*)ws;                         // 4 B
    signed char* w8p = (signed char*)(ws + 64);                       // 16 MiB
    signed char* x8 = (signed char*)(ws + 64 + (size_t)OUT_F * IN_F); // 32 MiB

    hipMemsetAsync(amax_u, 0, 4, stream);

    const int n_x4 = MDIM * IN_F / 4;     // 8,388,608 float4
    const int n_wt = 256 * 64 * 64;       // 1,048,576 repack threads (16B ea)

    amax_kernel<<<4096, 256, 0, stream>>>(x, n_x4, amax_u);
    prep_kernel<<<(n_x4 + n_wt + 255) / 256, 256, 0, stream>>>(
        x, w_int, x8, w8p, amax_u, n_x4, n_wt);

    const int nblocks = (MDIM / 256) * (OUT_F / 256);  // 512
    gemm_i8_kernel<<<nblocks, 512, 0, stream>>>(x8, w8p, amax_u, w_scale, bias,
                                                out);
}